// Round 16
// baseline (239.705 us; speedup 1.0000x reference)
//
#include <hip/hip_runtime.h>
#include <hip/hip_bf16.h>
#include <hip/hip_fp16.h>
#include <math.h>

// Problem constants
#define BB   2
#define CM   192        // D_MODEL
#define DI   384        // D_INNER
#define LL   16384      // D*H*W
#define NST  16         // D_STATE
#define RDT  12         // DT_RANK
#define XJ   44         // DT_RANK + 2*D_STATE
#define NC   512        // scan chunks
#define CLEN 32         // chunk length (NC*CLEN == LL)
#define NCH  (NC / 16)  // chunks per combine-thread
#define DBS  64         // dblT row stride (GEMM2 padded M)
#define XZS  768        // xzT row stride
#define CVT  32         // conv t-tile
#define BK   32         // GEMM k-tile

typedef __attribute__((ext_vector_type(8))) short bf16x8;
typedef __attribute__((ext_vector_type(4))) float f32x4;
typedef __attribute__((ext_vector_type(2))) float f32x2;
typedef unsigned short ushort_t;

static __device__ __forceinline__ ushort_t f2bf(float f) {
  __hip_bfloat16 h = __float2bfloat16(f);
  return *reinterpret_cast<ushort_t*>(&h);
}
static __device__ __forceinline__ float bf2f(ushort_t u) {
  __hip_bfloat16 h;
  *reinterpret_cast<ushort_t*>(&h) = u;
  return __bfloat162float(h);
}
static __device__ __forceinline__ ushort_t f2h(float f) {
  __half h = __float2half(f);
  return *reinterpret_cast<ushort_t*>(&h);
}
static __device__ __forceinline__ float h2f(ushort_t u) {
  __half h;
  *reinterpret_cast<ushort_t*>(&h) = u;
  return __half2float(h);
}

// ---------------------------------------------------------------------------
// PW = proj_w(192x192) @ out_proj_w(192x384)   (fp32, tiny)
__global__ __launch_bounds__(256) void fuse_proj_kernel(
    const float* __restrict__ pw, const float* __restrict__ ow, float* __restrict__ PW) {
  int idx = blockIdx.x * 256 + threadIdx.x;
  if (idx >= CM * DI) return;
  int o = idx / DI, d = idx % DI;
  float s = 0.f;
  #pragma unroll 4
  for (int c = 0; c < CM; c++) s += pw[o * CM + c] * ow[c * DI + d];
  PW[idx] = s;
}

// ---------------------------------------------------------------------------
// Weight conversions to bf16. Row-padding with zeros.
__global__ __launch_bounds__(256) void cvt_weights_kernel(
    const float* __restrict__ ipw, const float* __restrict__ xpw,
    const float* __restrict__ PW,
    ushort_t* __restrict__ ipw_bf, ushort_t* __restrict__ xpw_bf,
    ushort_t* __restrict__ PW_bf) {
  int i = blockIdx.x * 256 + threadIdx.x;
  if (i < 2 * DI * CM) ipw_bf[i] = f2bf(ipw[i]);
  if (i < 128 * DI) {
    int r = i / DI;
    xpw_bf[i] = (r < XJ) ? f2bf(xpw[i]) : (ushort_t)0;
  }
  if (i < 256 * DI) {
    int r = i / DI;
    PW_bf[i] = (r < CM) ? f2bf(PW[i]) : (ushort_t)0;
  }
}

// ---------------------------------------------------------------------------
// per-(b,c) mean / rstd over L
__global__ __launch_bounds__(256) void norm_stats_kernel(
    const float* __restrict__ x, float* __restrict__ mu, float* __restrict__ rstd) {
  int bc = blockIdx.x;
  const float* p = x + (size_t)bc * LL;
  float s = 0.f, ss = 0.f;
  for (int i = threadIdx.x * 4; i < LL; i += 256 * 4) {
    float4 v = *(const float4*)(p + i);
    s += v.x + v.y + v.z + v.w;
    ss += v.x * v.x + v.y * v.y + v.z * v.z + v.w * v.w;
  }
  for (int o = 32; o > 0; o >>= 1) {
    s += __shfl_down(s, o, 64);
    ss += __shfl_down(ss, o, 64);
  }
  __shared__ float sb[4], ssb[4];
  int wid = threadIdx.x >> 6;
  if ((threadIdx.x & 63) == 0) { sb[wid] = s; ssb[wid] = ss; }
  __syncthreads();
  if (threadIdx.x == 0) {
    s = sb[0] + sb[1] + sb[2] + sb[3];
    ss = ssb[0] + ssb[1] + ssb[2] + ssb[3];
    float m = s * (1.f / LL);
    float var = ss * (1.f / LL) - m * m;
    mu[bc] = m;
    rstd[bc] = 1.f / sqrtf(var + 1e-5f);
  }
}

// ---------------------------------------------------------------------------
// xT[b][t][c] bf16 = normalized x (LDS 64x64 transpose tile)
__global__ __launch_bounds__(256) void xt_norm_kernel(
    const float* __restrict__ x, const float* __restrict__ mu,
    const float* __restrict__ rstd, ushort_t* __restrict__ xT) {
  __shared__ ushort_t T[64][72];
  int t0 = blockIdx.x * 64, c0 = blockIdx.y * 64, b = blockIdx.z;
  int tid = threadIdx.x;
  int c = tid >> 2, tq = (tid & 3) * 16;
  int bc = b * CM + c0 + c;
  const float* xp = x + (size_t)bc * LL + t0 + tq;
  float m = mu[bc], rs = rstd[bc];
  #pragma unroll
  for (int j = 0; j < 16; j += 4) {
    float4 v = *(const float4*)(xp + j);
    T[c][tq + j + 0] = f2bf((v.x - m) * rs);
    T[c][tq + j + 1] = f2bf((v.y - m) * rs);
    T[c][tq + j + 2] = f2bf((v.z - m) * rs);
    T[c][tq + j + 3] = f2bf((v.w - m) * rs);
  }
  __syncthreads();
  int t = tid >> 2, cq = (tid & 3) * 16;
  unsigned int ob[8];
  #pragma unroll
  for (int j = 0; j < 8; j++)
    ob[j] = (unsigned int)T[cq + 2 * j][t] | ((unsigned int)T[cq + 2 * j + 1][t] << 16);
  ushort_t* op = xT + ((size_t)b * LL + t0 + t) * CM + c0 + cq;
  *(uint4*)(op)     = make_uint4(ob[0], ob[1], ob[2], ob[3]);
  *(uint4*)(op + 8) = make_uint4(ob[4], ob[5], ob[6], ob[7]);
}

// ---------------------------------------------------------------------------
// LDS-pipelined MFMA bf16 GEMM (BK=32 double-buffer, global_load_lds).
template <bool TOUT, typename OutT>
__global__ __launch_bounds__(256) void gemm_lds(
    const ushort_t* __restrict__ A, const ushort_t* __restrict__ BT,
    OutT* __restrict__ C, int K, int Mreal, int MT,
    long strideBT, long strideC, int ldc,
    const float* __restrict__ bias) {
  __shared__ ushort_t Asm[2][128 * BK];
  __shared__ ushort_t Bsm[2][128 * BK];

  int id = blockIdx.x;
  int per = MT * 8;
  int g = id / per, r = id % per;
  int nt = g * 8 + (r & 7);
  int mt = r >> 3;
  int b  = nt >> 7;
  long n0 = (long)(nt & 127) * 128;
  int m0 = mt * 128;

  int tid = threadIdx.x;
  int lane = tid & 63, wave = tid >> 6;
  const ushort_t* Bbase = BT + (size_t)b * strideBT;

  int srow0 = wave * 32 + (lane >> 2);
  int sk = (lane & 3) * 8;

  f32x4 acc[4][4];
  #pragma unroll
  for (int mi = 0; mi < 4; mi++)
    #pragma unroll
    for (int ni = 0; ni < 4; ni++) acc[mi][ni] = (f32x4){0.f, 0.f, 0.f, 0.f};

  int mh = wave & 1, nh = wave >> 1;
  int fr = lane & 15, fk = (lane >> 4) * 8;

  int nsteps = K / BK;
  {
    const ushort_t* As0 = A + (size_t)(m0 + srow0) * K + sk;
    const ushort_t* Bs0 = Bbase + (size_t)(n0 + srow0) * K + sk;
    __builtin_amdgcn_global_load_lds(As0, &Asm[0][wave * 1024], 16, 0, 0);
    __builtin_amdgcn_global_load_lds(As0 + (size_t)16 * K, &Asm[0][wave * 1024 + 512], 16, 0, 0);
    __builtin_amdgcn_global_load_lds(Bs0, &Bsm[0][wave * 1024], 16, 0, 0);
    __builtin_amdgcn_global_load_lds(Bs0 + (size_t)16 * K, &Bsm[0][wave * 1024 + 512], 16, 0, 0);
  }
  __syncthreads();
  int cur = 0;
  for (int s = 0; s < nsteps; s++) {
    if (s + 1 < nsteps) {
      int k0 = (s + 1) * BK;
      const ushort_t* As0 = A + (size_t)(m0 + srow0) * K + k0 + sk;
      const ushort_t* Bs0 = Bbase + (size_t)(n0 + srow0) * K + k0 + sk;
      __builtin_amdgcn_global_load_lds(As0, &Asm[cur ^ 1][wave * 1024], 16, 0, 0);
      __builtin_amdgcn_global_load_lds(As0 + (size_t)16 * K, &Asm[cur ^ 1][wave * 1024 + 512], 16, 0, 0);
      __builtin_amdgcn_global_load_lds(Bs0, &Bsm[cur ^ 1][wave * 1024], 16, 0, 0);
      __builtin_amdgcn_global_load_lds(Bs0 + (size_t)16 * K, &Bsm[cur ^ 1][wave * 1024 + 512], 16, 0, 0);
    }
    bf16x8 fa[4], fb[4];
    #pragma unroll
    for (int mi = 0; mi < 4; mi++)
      fa[mi] = *(const bf16x8*)&Asm[cur][(mh * 64 + mi * 16 + fr) * BK + fk];
    #pragma unroll
    for (int ni = 0; ni < 4; ni++)
      fb[ni] = *(const bf16x8*)&Bsm[cur][(nh * 64 + ni * 16 + fr) * BK + fk];
    #pragma unroll
    for (int mi = 0; mi < 4; mi++)
      #pragma unroll
      for (int ni = 0; ni < 4; ni++) {
        if constexpr (TOUT)
          acc[mi][ni] = __builtin_amdgcn_mfma_f32_16x16x32_bf16(fb[ni], fa[mi], acc[mi][ni], 0, 0, 0);
        else
          acc[mi][ni] = __builtin_amdgcn_mfma_f32_16x16x32_bf16(fa[mi], fb[ni], acc[mi][ni], 0, 0, 0);
      }
    __syncthreads();
    cur ^= 1;
  }

  int cq = (lane >> 4) * 4;
  if constexpr (TOUT) {
    #pragma unroll
    for (int ni = 0; ni < 4; ni++)
      #pragma unroll
      for (int rg = 0; rg < 4; rg++) {
        long n = n0 + nh * 64 + ni * 16 + cq + rg;
        OutT* cp = C + (size_t)b * strideC + n * ldc + m0 + mh * 64 + fr;
        #pragma unroll
        for (int mi = 0; mi < 4; mi++) {
          int mrow = m0 + mh * 64 + mi * 16 + fr;
          if (mrow < Mreal) {
            float v = acc[mi][ni][rg];
            if constexpr (sizeof(OutT) == 2) cp[mi * 16] = f2bf(v);
            else                             cp[mi * 16] = v;
          }
        }
      }
  } else {
    #pragma unroll
    for (int mi = 0; mi < 4; mi++)
      #pragma unroll
      for (int rg = 0; rg < 4; rg++) {
        int m = m0 + mh * 64 + mi * 16 + cq + rg;
        if (m < Mreal) {
          float bv = bias ? bias[m] : 0.f;
          OutT* cp = C + (size_t)b * strideC + (size_t)m * ldc + n0 + nh * 64 + fr;
          #pragma unroll
          for (int ni = 0; ni < 4; ni++)
            cp[ni * 16] = acc[mi][ni][rg] + bv;
        }
      }
  }
}

// ---------------------------------------------------------------------------
// Conv: causal depthwise k=4 + bias + SiLU.
// Writes u_t[b][t][d] bf16 (for GEMM2) AND u_s[b][d][t] bf16 (bulk, for scan).
__global__ __launch_bounds__(384) void conv_silu_kernel(
    const ushort_t* __restrict__ xzT, const float* __restrict__ conv_w,
    const float* __restrict__ conv_b, ushort_t* __restrict__ u_t,
    ushort_t* __restrict__ u_s) {
  __shared__ ushort_t Us[CVT + 3][DI];
  int t0 = blockIdx.x * CVT;
  int b = blockIdx.y;
  int tid = threadIdx.x;
  #pragma unroll
  for (int r = 0; r < CVT + 3; r++) {
    int t = t0 - 3 + r;
    Us[r][tid] = (t >= 0) ? xzT[((size_t)b * LL + t) * XZS + tid] : (ushort_t)0;
  }
  float w0 = conv_w[tid * 4 + 0], w1 = conv_w[tid * 4 + 1];
  float w2 = conv_w[tid * 4 + 2], w3 = conv_w[tid * 4 + 3];
  float cb = conv_b[tid];
  __syncthreads();
  ushort_t* up = u_t + ((size_t)b * LL + t0) * DI + tid;
  unsigned pk[CVT / 2];
  float xm3 = bf2f(Us[0][tid]);
  float xm2 = bf2f(Us[1][tid]);
  float xm1 = bf2f(Us[2][tid]);
  #pragma unroll
  for (int t = 0; t < CVT; t++) {
    float xc = bf2f(Us[t + 3][tid]);
    float a = cb + w3 * xc + w2 * xm1 + w1 * xm2 + w0 * xm3;
    float sv = a / (1.f + __expf(-a));
    ushort_t sb = f2bf(sv);
    up[(size_t)t * DI] = sb;
    if (t & 1) pk[t >> 1] |= ((unsigned)sb) << 16;
    else       pk[t >> 1] = (unsigned)sb;
    xm3 = xm2; xm2 = xm1; xm1 = xc;
  }
  ushort_t* usp = u_s + ((size_t)b * DI + tid) * LL + t0;
  #pragma unroll
  for (int g = 0; g < CVT / 8; g++)
    *(uint4*)(usp + g * 8) = make_uint4(pk[g*4], pk[g*4+1], pk[g*4+2], pk[g*4+3]);
}

// ---------------------------------------------------------------------------
// Scan phase 1 (dt fused, packed fp32). u read bulk from u_s[bd][t];
// dt16 written bulk to [bd][t]. B/dt_low via uniform s_loads.
__global__ __launch_bounds__(128) void scan_phase1(
    const ushort_t* __restrict__ u_s, const float* __restrict__ dblT,
    const float* __restrict__ A_log,
    const float* __restrict__ dtw, const float* __restrict__ dtb,
    float* __restrict__ hend, float* __restrict__ Sbuf,
    ushort_t* __restrict__ dt16) {
  int chunk = blockIdx.x, b = blockIdx.z;
  int d = blockIdx.y * 128 + threadIdx.x;
  int t0 = chunk * CLEN;
  const float* dblB = dblT + ((size_t)b * LL + t0) * DBS;  // uniform base
  int bd = b * DI + d;
  float av0 = -expf(A_log[d * NST]);
  float av_[NST];
  bool ok = true;
  #pragma unroll
  for (int j = 0; j < NST; j++) {
    av_[j] = -expf(A_log[d * NST + j]);
    ok = ok && (fabsf(av_[j] - av0 * (float)(j + 1)) <= 1e-4f * fabsf(av_[j]));
  }
  float w12[12];
  #pragma unroll
  for (int rr = 0; rr < 12; rr += 4)
    *(float4*)(w12 + rr) = *(const float4*)(dtw + d * 12 + rr);
  float db = dtb[d];
  const ushort_t* ubp = u_s + (size_t)bd * LL + t0;
  ushort_t* dtp = dt16 + (size_t)bd * LL + t0;
  float S = 0.f;

  size_t o = ((size_t)bd * NC + chunk) * NST;
  if (__all(ok)) {
    f32x2 h2[8];
    #pragma unroll
    for (int j = 0; j < 8; j++) h2[j] = (f32x2){0.f, 0.f};
    #pragma unroll
    for (int tg = 0; tg < CLEN; tg += 8) {
      uint4 uq = *(const uint4*)(ubp + tg);
      const unsigned* uw = (const unsigned*)&uq;
      unsigned dqw[4];
      #pragma unroll
      for (int k = 0; k < 8; k++) {
        int t = tg + k;
        float4 L0 = *(const float4*)(dblB + t * DBS + 0);
        float4 L1 = *(const float4*)(dblB + t * DBS + 4);
        float4 L2 = *(const float4*)(dblB + t * DBS + 8);
        float4 B0 = *(const float4*)(dblB + t * DBS + RDT + 0);
        float4 B1 = *(const float4*)(dblB + t * DBS + RDT + 4);
        float4 B2 = *(const float4*)(dblB + t * DBS + RDT + 8);
        float4 B3 = *(const float4*)(dblB + t * DBS + RDT + 12);
        float acc = db;
        acc = fmaf(L0.x, w12[0], acc); acc = fmaf(L0.y, w12[1], acc);
        acc = fmaf(L0.z, w12[2], acc); acc = fmaf(L0.w, w12[3], acc);
        acc = fmaf(L1.x, w12[4], acc); acc = fmaf(L1.y, w12[5], acc);
        acc = fmaf(L1.z, w12[6], acc); acc = fmaf(L1.w, w12[7], acc);
        acc = fmaf(L2.x, w12[8], acc); acc = fmaf(L2.y, w12[9], acc);
        acc = fmaf(L2.z, w12[10], acc); acc = fmaf(L2.w, w12[11], acc);
        float dtv = (acc > 15.f) ? acc : __logf(1.f + __expf(acc));
        unsigned dh = (unsigned)f2h(dtv);
        if (k & 1) dqw[k >> 1] |= dh << 16;
        else       dqw[k >> 1] = dh;
        float uv = bf2f((ushort_t)(uw[k >> 1] >> ((k & 1) * 16)));
        float q = dtv * uv;
        S += dtv;
        float p1 = __expf(dtv * av0);
        float p2 = p1 * p1, p4 = p2 * p2, p8 = p4 * p4;
        f32x2 p2v = {p2, p2}, p4v = {p4, p4}, p8v = {p8, p8};
        f32x2 P0 = {p1, p2};
        f32x2 P1 = P0 * p2v;
        f32x2 P2 = P0 * p4v;
        f32x2 P3 = P1 * p4v;
        f32x2 P4 = P0 * p8v;
        f32x2 P5 = P1 * p8v;
        f32x2 P6 = P2 * p8v;
        f32x2 P7 = P3 * p8v;
        f32x2 qv = {q, q};
        h2[0] = P0 * h2[0] + qv * (f32x2){B0.x, B0.y};
        h2[1] = P1 * h2[1] + qv * (f32x2){B0.z, B0.w};
        h2[2] = P2 * h2[2] + qv * (f32x2){B1.x, B1.y};
        h2[3] = P3 * h2[3] + qv * (f32x2){B1.z, B1.w};
        h2[4] = P4 * h2[4] + qv * (f32x2){B2.x, B2.y};
        h2[5] = P5 * h2[5] + qv * (f32x2){B2.z, B2.w};
        h2[6] = P6 * h2[6] + qv * (f32x2){B3.x, B3.y};
        h2[7] = P7 * h2[7] + qv * (f32x2){B3.z, B3.w};
      }
      *(uint4*)(dtp + tg) = make_uint4(dqw[0], dqw[1], dqw[2], dqw[3]);
    }
    #pragma unroll
    for (int j = 0; j < 8; j += 2)
      *(float4*)(hend + o + j * 2) =
          make_float4(h2[j].x, h2[j].y, h2[j + 1].x, h2[j + 1].y);
  } else {
    float h[NST];
    #pragma unroll
    for (int j = 0; j < NST; j++) h[j] = 0.f;
    for (int t = 0; t < CLEN; t++) {
      float acc = db;
      #pragma unroll
      for (int rr = 0; rr < 12; rr++) acc = fmaf(dblB[t * DBS + rr], w12[rr], acc);
      float dtv = (acc > 15.f) ? acc : __logf(1.f + __expf(acc));
      dtp[t] = f2h(dtv);
      float uv  = bf2f(ubp[t]);
      float q = dtv * uv;
      S += dtv;
      #pragma unroll
      for (int j = 0; j < NST; j++)
        h[j] = __expf(dtv * av_[j]) * h[j] + q * dblB[t * DBS + RDT + j];
    }
    #pragma unroll
    for (int j = 0; j < NST; j++) hend[o + j] = h[j];
  }
  Sbuf[(size_t)bd * NC + chunk] = S;
}

// ---------------------------------------------------------------------------
// Scan combine: decay products reconstructed as exp(S * av_s) from Sbuf.
__global__ __launch_bounds__(256) void scan_combine(
    float* __restrict__ hend, const float* __restrict__ Sbuf,
    const float* __restrict__ A_log) {
  __shared__ float sP[16][16], sH[16][16];
  int bd = blockIdx.x;
  int d = bd % DI;
  int s = threadIdx.x & 15, g = threadIdx.x >> 4;
  float av = -expf(A_log[d * NST + s]);
  size_t baseS = (size_t)bd * NC + g * NCH;
  size_t base = ((size_t)bd * NC + g * NCH) * NST + s;
  float Pl = 1.f, Hl = 0.f;
  #pragma unroll
  for (int k = 0; k < NCH; k++) {
    float p = __expf(Sbuf[baseS + k] * av);
    Hl = fmaf(p, Hl, hend[base + (size_t)k * NST]);
    Pl *= p;
  }
  sP[g][s] = Pl; sH[g][s] = Hl;
  __syncthreads();
  if (threadIdx.x < 16) {
    int ss = threadIdx.x;
    float c = 0.f;
    #pragma unroll
    for (int gg = 0; gg < 16; gg++) {
      float tmp = sH[gg][ss];
      float pp  = sP[gg][ss];
      sH[gg][ss] = c;
      c = fmaf(pp, c, tmp);
    }
  }
  __syncthreads();
  float c = sH[g][s];
  #pragma unroll
  for (int k = 0; k < NCH; k++) {
    size_t o = base + (size_t)k * NST;
    float p = __expf(Sbuf[baseS + k] * av);
    float he = hend[o];
    hend[o] = c;
    c = fmaf(p, c, he);
  }
}

// ---------------------------------------------------------------------------
// Scan phase 3: dt16/u_s read bulk [bd][t]; B/C via uniform s_loads (R11 arm);
// z strided; packed fp32 update; ym_t[t][d] bf16.
__global__ __launch_bounds__(128) void scan_phase3(
    const ushort_t* __restrict__ u_s, const float* __restrict__ dblT,
    const float* __restrict__ A_log, const ushort_t* __restrict__ dt16,
    const float* __restrict__ hin, const float* __restrict__ Dp,
    const ushort_t* __restrict__ xzT, ushort_t* __restrict__ ym_t) {
  int chunk = blockIdx.x, b = blockIdx.z;
  int d = blockIdx.y * 128 + threadIdx.x;
  int t0 = chunk * CLEN;
  const float* dblB = dblT + ((size_t)b * LL + t0) * DBS;  // uniform base
  int bd = b * DI + d;
  float av0 = -expf(A_log[d * NST]);
  float av_[NST];
  bool ok = true;
  #pragma unroll
  for (int j = 0; j < NST; j++) {
    av_[j] = -expf(A_log[d * NST + j]);
    ok = ok && (fabsf(av_[j] - av0 * (float)(j + 1)) <= 1e-4f * fabsf(av_[j]));
  }
  const ushort_t* ubp = u_s + (size_t)bd * LL + t0;
  const ushort_t* dtp = dt16 + (size_t)bd * LL + t0;
  const ushort_t* zp = xzT + ((size_t)b * LL + t0) * XZS + DI + d;
  ushort_t* ymp = ym_t + ((size_t)b * LL + t0) * DI + d;

  const float* hi = hin + ((size_t)bd * NC + chunk) * NST;
  float Dv = Dp[d];

  if (__all(ok)) {
    f32x2 h2[8];
    #pragma unroll
    for (int j = 0; j < 8; j += 2) {
      float4 v = *(const float4*)(hi + j * 2);
      h2[j]     = (f32x2){v.x, v.y};
      h2[j + 1] = (f32x2){v.z, v.w};
    }
    #pragma unroll
    for (int tg = 0; tg < CLEN; tg += 8) {
      uint4 uq = *(const uint4*)(ubp + tg);
      uint4 dq = *(const uint4*)(dtp + tg);
      const unsigned* uw = (const unsigned*)&uq;
      const unsigned* dw = (const unsigned*)&dq;
      #pragma unroll
      for (int k = 0; k < 8; k++) {
        int t = tg + k;
        float4 B0 = *(const float4*)(dblB + t * DBS + RDT + 0);
        float4 B1 = *(const float4*)(dblB + t * DBS + RDT + 4);
        float4 B2 = *(const float4*)(dblB + t * DBS + RDT + 8);
        float4 B3 = *(const float4*)(dblB + t * DBS + RDT + 12);
        float4 C0 = *(const float4*)(dblB + t * DBS + RDT + 16);
        float4 C1 = *(const float4*)(dblB + t * DBS + RDT + 20);
        float4 C2 = *(const float4*)(dblB + t * DBS + RDT + 24);
        float4 C3 = *(const float4*)(dblB + t * DBS + RDT + 28);
        float dtv = h2f((ushort_t)(dw[k >> 1] >> ((k & 1) * 16)));
        float uv  = bf2f((ushort_t)(uw[k >> 1] >> ((k & 1) * 16)));
        float zv  = bf2f(zp[(size_t)t * XZS]);
        float q = dtv * uv;
        float p1 = __expf(dtv * av0);
        float p2 = p1 * p1, p4 = p2 * p2, p8 = p4 * p4;
        f32x2 p2v = {p2, p2}, p4v = {p4, p4}, p8v = {p8, p8};
        f32x2 P0 = {p1, p2};
        f32x2 P1 = P0 * p2v;
        f32x2 P2 = P0 * p4v;
        f32x2 P3 = P1 * p4v;
        f32x2 P4 = P0 * p8v;
        f32x2 P5 = P1 * p8v;
        f32x2 P6 = P2 * p8v;
        f32x2 P7 = P3 * p8v;
        f32x2 qv = {q, q};
        f32x2 ya, yb;
        h2[0] = P0 * h2[0] + qv * (f32x2){B0.x, B0.y};  ya = h2[0] * (f32x2){C0.x, C0.y};
        h2[1] = P1 * h2[1] + qv * (f32x2){B0.z, B0.w};  yb = h2[1] * (f32x2){C0.z, C0.w};
        h2[2] = P2 * h2[2] + qv * (f32x2){B1.x, B1.y};  ya = h2[2] * (f32x2){C1.x, C1.y} + ya;
        h2[3] = P3 * h2[3] + qv * (f32x2){B1.z, B1.w};  yb = h2[3] * (f32x2){C1.z, C1.w} + yb;
        h2[4] = P4 * h2[4] + qv * (f32x2){B2.x, B2.y};  ya = h2[4] * (f32x2){C2.x, C2.y} + ya;
        h2[5] = P5 * h2[5] + qv * (f32x2){B2.z, B2.w};  yb = h2[5] * (f32x2){C2.z, C2.w} + yb;
        h2[6] = P6 * h2[6] + qv * (f32x2){B3.x, B3.y};  ya = h2[6] * (f32x2){C3.x, C3.y} + ya;
        h2[7] = P7 * h2[7] + qv * (f32x2){B3.z, B3.w};  yb = h2[7] * (f32x2){C3.z, C3.w} + yb;
        float y = (ya.x + ya.y) + (yb.x + yb.y);
        float yv = (y + uv * Dv) * (zv / (1.f + __expf(-zv)));
        ymp[(size_t)t * DI] = f2bf(yv);
      }
    }
  } else {
    float h[NST];
    #pragma unroll
    for (int j = 0; j < NST; j++) h[j] = hi[j];
    for (int t = 0; t < CLEN; t++) {
      float dtv = h2f(dtp[t]);
      float uv  = bf2f(ubp[t]);
      float zv  = bf2f(zp[(size_t)t * XZS]);
      float q = dtv * uv;
      float y = 0.f;
      #pragma unroll
      for (int j = 0; j < NST; j++) {
        h[j] = __expf(dtv * av_[j]) * h[j] + q * dblB[t * DBS + RDT + j];
        y = fmaf(h[j], dblB[t * DBS + RDT + NST + j], y);
      }
      float yv = (y + uv * Dv) * (zv / (1.f + __expf(-zv)));
      ymp[(size_t)t * DI] = f2bf(yv);
    }
  }
}

// ---------------------------------------------------------------------------
extern "C" void kernel_launch(void* const* d_in, const int* in_sizes, int n_in,
                              void* d_out, int out_size, void* d_ws, size_t ws_size,
                              hipStream_t stream) {
  const float* x         = (const float*)d_in[0];
  const float* in_proj_w = (const float*)d_in[1];
  const float* conv_w    = (const float*)d_in[2];
  const float* conv_b    = (const float*)d_in[3];
  const float* x_proj_w  = (const float*)d_in[4];
  const float* dt_proj_w = (const float*)d_in[5];
  const float* dt_proj_b = (const float*)d_in[6];
  const float* A_log     = (const float*)d_in[7];
  const float* D_param   = (const float*)d_in[8];
  const float* out_proj_w= (const float*)d_in[9];
  const float* proj_w    = (const float*)d_in[10];
  const float* proj_b    = (const float*)d_in[11];
  float* out = (float*)d_out;

  // workspace layout (float units)
  float* w = (float*)d_ws;
  float*    mu     = w;                                   // 512
  float*    rstd   = w + 512;                             // 512
  float*    PW     = w + 1024;                            // 73,728
  ushort_t* PW_bf  = (ushort_t*)(w + 74752);              // 256x384 bf16 (49,152 f)
  ushort_t* ipw_bf = (ushort_t*)(w + 123904);             // 768x192 bf16 (73,728 f)
  ushort_t* xpw_bf = (ushort_t*)(w + 197632);             // 128x384 bf16 (24,576 f)
  ushort_t* xT     = (ushort_t*)(w + 222208);             // 6.29M bf16 (3,145,728 f)
  ushort_t* xzT    = (ushort_t*)(w + 3367936);            // 25.2M bf16 (12,582,912 f)
  ushort_t* u_t    = (ushort_t*)(w + 15950848);           // 12.6M bf16 (6,291,456 f)
  float*    dblT   = w + 22242304;                        // 2,097,152 f
  ushort_t* ym_t   = (ushort_t*)(w + 24339456);           // 12.6M bf16 (6,291,456 f)
  float*    hend   = w + 30630912;                        // 6,291,456 f (NC=512)
  float*    Sbuf   = w + 36922368;                        // 393,216 f
  ushort_t* dt16   = (ushort_t*)(w + 37315584);           // 12.6M fp16 (6,291,456 f) [bd][t]
  ushort_t* u_s    = (ushort_t*)(w + 43607040);           // 12.6M bf16 (6,291,456 f) [bd][t]
  size_t need = 49898496;
  if (ws_size < need * sizeof(float)) return;

  norm_stats_kernel<<<dim3(BB * CM), dim3(256), 0, stream>>>(x, mu, rstd);
  fuse_proj_kernel<<<dim3((CM * DI + 255) / 256), dim3(256), 0, stream>>>(proj_w, out_proj_w, PW);
  cvt_weights_kernel<<<dim3((2 * DI * CM + 255) / 256), dim3(256), 0, stream>>>(
      in_proj_w, x_proj_w, PW, ipw_bf, xpw_bf, PW_bf);
  xt_norm_kernel<<<dim3(LL / 64, CM / 64, BB), dim3(256), 0, stream>>>(x, mu, rstd, xT);

  // GEMM1: xzT[b][t][768] = xT(BT) x in_proj_w   (M=768 => MT=6, K=192)
  gemm_lds<true, ushort_t><<<dim3(256 * 6), dim3(256), 0, stream>>>(
      ipw_bf, xT, xzT, CM, 768, 6, (long)LL * CM, (long)LL * XZS, XZS, nullptr);

  conv_silu_kernel<<<dim3(LL / CVT, BB), dim3(384), 0, stream>>>(xzT, conv_w, conv_b, u_t, u_s);

  // GEMM2: dblT[b][t][64] = u_t(BT) x x_proj_w(padded 128)  (Mreal=64, MT=1, K=384)
  gemm_lds<true, float><<<dim3(256 * 1), dim3(256), 0, stream>>>(
      xpw_bf, u_t, dblT, DI, 64, 1, (long)LL * DI, (long)LL * DBS, DBS, nullptr);

  scan_phase1<<<dim3(NC, 3, BB), dim3(128), 0, stream>>>(
      u_s, dblT, A_log, dt_proj_w, dt_proj_b, hend, Sbuf, dt16);
  scan_combine<<<dim3(BB * DI), dim3(256), 0, stream>>>(hend, Sbuf, A_log);
  scan_phase3<<<dim3(NC, 3, BB), dim3(128), 0, stream>>>(
      u_s, dblT, A_log, dt16, hend, D_param, xzT, ym_t);

  // GEMM3: out[b][192][L] = PW(padded 256) x ym_t(BT) + proj_b  (Mreal=192, MT=2, K=384)
  gemm_lds<false, float><<<dim3(256 * 2), dim3(256), 0, stream>>>(
      PW_bf, ym_t, out, DI, CM, 2, (long)LL * DI, (long)CM * LL, LL, proj_b);
}

// Round 17
// 231.744 us; speedup vs baseline: 1.0344x; 1.0344x over previous
//
#include <hip/hip_runtime.h>
#include <hip/hip_bf16.h>
#include <hip/hip_fp16.h>
#include <math.h>

// Problem constants
#define BB   2
#define CM   192        // D_MODEL
#define DI   384        // D_INNER
#define LL   16384      // D*H*W
#define NST  16         // D_STATE
#define RDT  12         // DT_RANK
#define XJ   44         // DT_RANK + 2*D_STATE
#define NC   512        // scan chunks
#define CLEN 32         // chunk length (NC*CLEN == LL)
#define NCH  (NC / 16)  // chunks per combine-thread
#define DBS  64         // dblT row stride (GEMM2 padded M)
#define XZS  768        // xzT row stride
#define CVT  32         // conv t-tile
#define BK   32         // GEMM k-tile

typedef __attribute__((ext_vector_type(8))) short bf16x8;
typedef __attribute__((ext_vector_type(4))) float f32x4;
typedef __attribute__((ext_vector_type(2))) float f32x2;
typedef unsigned short ushort_t;

static __device__ __forceinline__ ushort_t f2bf(float f) {
  __hip_bfloat16 h = __float2bfloat16(f);
  return *reinterpret_cast<ushort_t*>(&h);
}
static __device__ __forceinline__ float bf2f(ushort_t u) {
  __hip_bfloat16 h;
  *reinterpret_cast<ushort_t*>(&h) = u;
  return __bfloat162float(h);
}
static __device__ __forceinline__ ushort_t f2h(float f) {
  __half h = __float2half(f);
  return *reinterpret_cast<ushort_t*>(&h);
}
static __device__ __forceinline__ float h2f(ushort_t u) {
  __half h;
  *reinterpret_cast<ushort_t*>(&h) = u;
  return __half2float(h);
}

// ---------------------------------------------------------------------------
// PW = proj_w(192x192) @ out_proj_w(192x384)   (fp32, tiny)
__global__ __launch_bounds__(256) void fuse_proj_kernel(
    const float* __restrict__ pw, const float* __restrict__ ow, float* __restrict__ PW) {
  int idx = blockIdx.x * 256 + threadIdx.x;
  if (idx >= CM * DI) return;
  int o = idx / DI, d = idx % DI;
  float s = 0.f;
  #pragma unroll 4
  for (int c = 0; c < CM; c++) s += pw[o * CM + c] * ow[c * DI + d];
  PW[idx] = s;
}

// ---------------------------------------------------------------------------
// Weight conversions to bf16. Row-padding with zeros.
__global__ __launch_bounds__(256) void cvt_weights_kernel(
    const float* __restrict__ ipw, const float* __restrict__ xpw,
    const float* __restrict__ PW,
    ushort_t* __restrict__ ipw_bf, ushort_t* __restrict__ xpw_bf,
    ushort_t* __restrict__ PW_bf) {
  int i = blockIdx.x * 256 + threadIdx.x;
  if (i < 2 * DI * CM) ipw_bf[i] = f2bf(ipw[i]);
  if (i < 128 * DI) {
    int r = i / DI;
    xpw_bf[i] = (r < XJ) ? f2bf(xpw[i]) : (ushort_t)0;
  }
  if (i < 256 * DI) {
    int r = i / DI;
    PW_bf[i] = (r < CM) ? f2bf(PW[i]) : (ushort_t)0;
  }
}

// ---------------------------------------------------------------------------
// per-(b,c) mean / rstd over L
__global__ __launch_bounds__(256) void norm_stats_kernel(
    const float* __restrict__ x, float* __restrict__ mu, float* __restrict__ rstd) {
  int bc = blockIdx.x;
  const float* p = x + (size_t)bc * LL;
  float s = 0.f, ss = 0.f;
  for (int i = threadIdx.x * 4; i < LL; i += 256 * 4) {
    float4 v = *(const float4*)(p + i);
    s += v.x + v.y + v.z + v.w;
    ss += v.x * v.x + v.y * v.y + v.z * v.z + v.w * v.w;
  }
  for (int o = 32; o > 0; o >>= 1) {
    s += __shfl_down(s, o, 64);
    ss += __shfl_down(ss, o, 64);
  }
  __shared__ float sb[4], ssb[4];
  int wid = threadIdx.x >> 6;
  if ((threadIdx.x & 63) == 0) { sb[wid] = s; ssb[wid] = ss; }
  __syncthreads();
  if (threadIdx.x == 0) {
    s = sb[0] + sb[1] + sb[2] + sb[3];
    ss = ssb[0] + ssb[1] + ssb[2] + ssb[3];
    float m = s * (1.f / LL);
    float var = ss * (1.f / LL) - m * m;
    mu[bc] = m;
    rstd[bc] = 1.f / sqrtf(var + 1e-5f);
  }
}

// ---------------------------------------------------------------------------
// xT[b][t][c] bf16 = normalized x (LDS 64x64 transpose tile)
__global__ __launch_bounds__(256) void xt_norm_kernel(
    const float* __restrict__ x, const float* __restrict__ mu,
    const float* __restrict__ rstd, ushort_t* __restrict__ xT) {
  __shared__ ushort_t T[64][72];
  int t0 = blockIdx.x * 64, c0 = blockIdx.y * 64, b = blockIdx.z;
  int tid = threadIdx.x;
  int c = tid >> 2, tq = (tid & 3) * 16;
  int bc = b * CM + c0 + c;
  const float* xp = x + (size_t)bc * LL + t0 + tq;
  float m = mu[bc], rs = rstd[bc];
  #pragma unroll
  for (int j = 0; j < 16; j += 4) {
    float4 v = *(const float4*)(xp + j);
    T[c][tq + j + 0] = f2bf((v.x - m) * rs);
    T[c][tq + j + 1] = f2bf((v.y - m) * rs);
    T[c][tq + j + 2] = f2bf((v.z - m) * rs);
    T[c][tq + j + 3] = f2bf((v.w - m) * rs);
  }
  __syncthreads();
  int t = tid >> 2, cq = (tid & 3) * 16;
  unsigned int ob[8];
  #pragma unroll
  for (int j = 0; j < 8; j++)
    ob[j] = (unsigned int)T[cq + 2 * j][t] | ((unsigned int)T[cq + 2 * j + 1][t] << 16);
  ushort_t* op = xT + ((size_t)b * LL + t0 + t) * CM + c0 + cq;
  *(uint4*)(op)     = make_uint4(ob[0], ob[1], ob[2], ob[3]);
  *(uint4*)(op + 8) = make_uint4(ob[4], ob[5], ob[6], ob[7]);
}

// ---------------------------------------------------------------------------
// LDS-pipelined MFMA bf16 GEMM (BK=32 double-buffer, global_load_lds).
template <bool TOUT, typename OutT>
__global__ __launch_bounds__(256) void gemm_lds(
    const ushort_t* __restrict__ A, const ushort_t* __restrict__ BT,
    OutT* __restrict__ C, int K, int Mreal, int MT,
    long strideBT, long strideC, int ldc,
    const float* __restrict__ bias) {
  __shared__ ushort_t Asm[2][128 * BK];
  __shared__ ushort_t Bsm[2][128 * BK];

  int id = blockIdx.x;
  int per = MT * 8;
  int g = id / per, r = id % per;
  int nt = g * 8 + (r & 7);
  int mt = r >> 3;
  int b  = nt >> 7;
  long n0 = (long)(nt & 127) * 128;
  int m0 = mt * 128;

  int tid = threadIdx.x;
  int lane = tid & 63, wave = tid >> 6;
  const ushort_t* Bbase = BT + (size_t)b * strideBT;

  int srow0 = wave * 32 + (lane >> 2);
  int sk = (lane & 3) * 8;

  f32x4 acc[4][4];
  #pragma unroll
  for (int mi = 0; mi < 4; mi++)
    #pragma unroll
    for (int ni = 0; ni < 4; ni++) acc[mi][ni] = (f32x4){0.f, 0.f, 0.f, 0.f};

  int mh = wave & 1, nh = wave >> 1;
  int fr = lane & 15, fk = (lane >> 4) * 8;

  int nsteps = K / BK;
  {
    const ushort_t* As0 = A + (size_t)(m0 + srow0) * K + sk;
    const ushort_t* Bs0 = Bbase + (size_t)(n0 + srow0) * K + sk;
    __builtin_amdgcn_global_load_lds(As0, &Asm[0][wave * 1024], 16, 0, 0);
    __builtin_amdgcn_global_load_lds(As0 + (size_t)16 * K, &Asm[0][wave * 1024 + 512], 16, 0, 0);
    __builtin_amdgcn_global_load_lds(Bs0, &Bsm[0][wave * 1024], 16, 0, 0);
    __builtin_amdgcn_global_load_lds(Bs0 + (size_t)16 * K, &Bsm[0][wave * 1024 + 512], 16, 0, 0);
  }
  __syncthreads();
  int cur = 0;
  for (int s = 0; s < nsteps; s++) {
    if (s + 1 < nsteps) {
      int k0 = (s + 1) * BK;
      const ushort_t* As0 = A + (size_t)(m0 + srow0) * K + k0 + sk;
      const ushort_t* Bs0 = Bbase + (size_t)(n0 + srow0) * K + k0 + sk;
      __builtin_amdgcn_global_load_lds(As0, &Asm[cur ^ 1][wave * 1024], 16, 0, 0);
      __builtin_amdgcn_global_load_lds(As0 + (size_t)16 * K, &Asm[cur ^ 1][wave * 1024 + 512], 16, 0, 0);
      __builtin_amdgcn_global_load_lds(Bs0, &Bsm[cur ^ 1][wave * 1024], 16, 0, 0);
      __builtin_amdgcn_global_load_lds(Bs0 + (size_t)16 * K, &Bsm[cur ^ 1][wave * 1024 + 512], 16, 0, 0);
    }
    bf16x8 fa[4], fb[4];
    #pragma unroll
    for (int mi = 0; mi < 4; mi++)
      fa[mi] = *(const bf16x8*)&Asm[cur][(mh * 64 + mi * 16 + fr) * BK + fk];
    #pragma unroll
    for (int ni = 0; ni < 4; ni++)
      fb[ni] = *(const bf16x8*)&Bsm[cur][(nh * 64 + ni * 16 + fr) * BK + fk];
    #pragma unroll
    for (int mi = 0; mi < 4; mi++)
      #pragma unroll
      for (int ni = 0; ni < 4; ni++) {
        if constexpr (TOUT)
          acc[mi][ni] = __builtin_amdgcn_mfma_f32_16x16x32_bf16(fb[ni], fa[mi], acc[mi][ni], 0, 0, 0);
        else
          acc[mi][ni] = __builtin_amdgcn_mfma_f32_16x16x32_bf16(fa[mi], fb[ni], acc[mi][ni], 0, 0, 0);
      }
    __syncthreads();
    cur ^= 1;
  }

  int cq = (lane >> 4) * 4;
  if constexpr (TOUT) {
    #pragma unroll
    for (int ni = 0; ni < 4; ni++)
      #pragma unroll
      for (int rg = 0; rg < 4; rg++) {
        long n = n0 + nh * 64 + ni * 16 + cq + rg;
        OutT* cp = C + (size_t)b * strideC + n * ldc + m0 + mh * 64 + fr;
        #pragma unroll
        for (int mi = 0; mi < 4; mi++) {
          int mrow = m0 + mh * 64 + mi * 16 + fr;
          if (mrow < Mreal) {
            float v = acc[mi][ni][rg];
            if constexpr (sizeof(OutT) == 2) cp[mi * 16] = f2bf(v);
            else                             cp[mi * 16] = v;
          }
        }
      }
  } else {
    #pragma unroll
    for (int mi = 0; mi < 4; mi++)
      #pragma unroll
      for (int rg = 0; rg < 4; rg++) {
        int m = m0 + mh * 64 + mi * 16 + cq + rg;
        if (m < Mreal) {
          float bv = bias ? bias[m] : 0.f;
          OutT* cp = C + (size_t)b * strideC + (size_t)m * ldc + n0 + nh * 64 + fr;
          #pragma unroll
          for (int ni = 0; ni < 4; ni++)
            cp[ni * 16] = acc[mi][ni][rg] + bv;
        }
      }
  }
}

// ---------------------------------------------------------------------------
// Conv: causal depthwise k=4 + bias + SiLU.
// Writes u_t[b][t][d] bf16 (for GEMM2) AND u_s[b][d][t] bf16 (bulk, for scan).
__global__ __launch_bounds__(384) void conv_silu_kernel(
    const ushort_t* __restrict__ xzT, const float* __restrict__ conv_w,
    const float* __restrict__ conv_b, ushort_t* __restrict__ u_t,
    ushort_t* __restrict__ u_s) {
  __shared__ ushort_t Us[CVT + 3][DI];
  int t0 = blockIdx.x * CVT;
  int b = blockIdx.y;
  int tid = threadIdx.x;
  #pragma unroll
  for (int r = 0; r < CVT + 3; r++) {
    int t = t0 - 3 + r;
    Us[r][tid] = (t >= 0) ? xzT[((size_t)b * LL + t) * XZS + tid] : (ushort_t)0;
  }
  float w0 = conv_w[tid * 4 + 0], w1 = conv_w[tid * 4 + 1];
  float w2 = conv_w[tid * 4 + 2], w3 = conv_w[tid * 4 + 3];
  float cb = conv_b[tid];
  __syncthreads();
  ushort_t* up = u_t + ((size_t)b * LL + t0) * DI + tid;
  unsigned pk[CVT / 2];
  float xm3 = bf2f(Us[0][tid]);
  float xm2 = bf2f(Us[1][tid]);
  float xm1 = bf2f(Us[2][tid]);
  #pragma unroll
  for (int t = 0; t < CVT; t++) {
    float xc = bf2f(Us[t + 3][tid]);
    float a = cb + w3 * xc + w2 * xm1 + w1 * xm2 + w0 * xm3;
    float sv = a / (1.f + __expf(-a));
    ushort_t sb = f2bf(sv);
    up[(size_t)t * DI] = sb;
    if (t & 1) pk[t >> 1] |= ((unsigned)sb) << 16;
    else       pk[t >> 1] = (unsigned)sb;
    xm3 = xm2; xm2 = xm1; xm1 = xc;
  }
  ushort_t* usp = u_s + ((size_t)b * DI + tid) * LL + t0;
  #pragma unroll
  for (int g = 0; g < CVT / 8; g++)
    *(uint4*)(usp + g * 8) = make_uint4(pk[g*4], pk[g*4+1], pk[g*4+2], pk[g*4+3]);
}

// ---------------------------------------------------------------------------
// Scan phase 1 (dt fused, packed fp32). u read bulk from u_s[bd][t];
// dt16 written bulk to [bd][t]. B/dt_low via uniform s_loads.
__global__ __launch_bounds__(128) void scan_phase1(
    const ushort_t* __restrict__ u_s, const float* __restrict__ dblT,
    const float* __restrict__ A_log,
    const float* __restrict__ dtw, const float* __restrict__ dtb,
    float* __restrict__ hend, float* __restrict__ Sbuf,
    ushort_t* __restrict__ dt16) {
  int chunk = blockIdx.x, b = blockIdx.z;
  int d = blockIdx.y * 128 + threadIdx.x;
  int t0 = chunk * CLEN;
  const float* dblB = dblT + ((size_t)b * LL + t0) * DBS;  // uniform base
  int bd = b * DI + d;
  float av0 = -expf(A_log[d * NST]);
  float av_[NST];
  bool ok = true;
  #pragma unroll
  for (int j = 0; j < NST; j++) {
    av_[j] = -expf(A_log[d * NST + j]);
    ok = ok && (fabsf(av_[j] - av0 * (float)(j + 1)) <= 1e-4f * fabsf(av_[j]));
  }
  float w12[12];
  #pragma unroll
  for (int rr = 0; rr < 12; rr += 4)
    *(float4*)(w12 + rr) = *(const float4*)(dtw + d * 12 + rr);
  float db = dtb[d];
  const ushort_t* ubp = u_s + (size_t)bd * LL + t0;
  ushort_t* dtp = dt16 + (size_t)bd * LL + t0;
  float S = 0.f;

  size_t o = ((size_t)bd * NC + chunk) * NST;
  if (__all(ok)) {
    f32x2 h2[8];
    #pragma unroll
    for (int j = 0; j < 8; j++) h2[j] = (f32x2){0.f, 0.f};
    #pragma unroll
    for (int tg = 0; tg < CLEN; tg += 8) {
      uint4 uq = *(const uint4*)(ubp + tg);
      const unsigned* uw = (const unsigned*)&uq;
      unsigned dqw[4];
      #pragma unroll
      for (int k = 0; k < 8; k++) {
        int t = tg + k;
        float4 L0 = *(const float4*)(dblB + t * DBS + 0);
        float4 L1 = *(const float4*)(dblB + t * DBS + 4);
        float4 L2 = *(const float4*)(dblB + t * DBS + 8);
        float4 B0 = *(const float4*)(dblB + t * DBS + RDT + 0);
        float4 B1 = *(const float4*)(dblB + t * DBS + RDT + 4);
        float4 B2 = *(const float4*)(dblB + t * DBS + RDT + 8);
        float4 B3 = *(const float4*)(dblB + t * DBS + RDT + 12);
        float acc = db;
        acc = fmaf(L0.x, w12[0], acc); acc = fmaf(L0.y, w12[1], acc);
        acc = fmaf(L0.z, w12[2], acc); acc = fmaf(L0.w, w12[3], acc);
        acc = fmaf(L1.x, w12[4], acc); acc = fmaf(L1.y, w12[5], acc);
        acc = fmaf(L1.z, w12[6], acc); acc = fmaf(L1.w, w12[7], acc);
        acc = fmaf(L2.x, w12[8], acc); acc = fmaf(L2.y, w12[9], acc);
        acc = fmaf(L2.z, w12[10], acc); acc = fmaf(L2.w, w12[11], acc);
        float dtv = (acc > 15.f) ? acc : __logf(1.f + __expf(acc));
        unsigned dh = (unsigned)f2h(dtv);
        if (k & 1) dqw[k >> 1] |= dh << 16;
        else       dqw[k >> 1] = dh;
        float uv = bf2f((ushort_t)(uw[k >> 1] >> ((k & 1) * 16)));
        float q = dtv * uv;
        S += dtv;
        float p1 = __expf(dtv * av0);
        float p2 = p1 * p1, p4 = p2 * p2, p8 = p4 * p4;
        f32x2 p2v = {p2, p2}, p4v = {p4, p4}, p8v = {p8, p8};
        f32x2 P0 = {p1, p2};
        f32x2 P1 = P0 * p2v;
        f32x2 P2 = P0 * p4v;
        f32x2 P3 = P1 * p4v;
        f32x2 P4 = P0 * p8v;
        f32x2 P5 = P1 * p8v;
        f32x2 P6 = P2 * p8v;
        f32x2 P7 = P3 * p8v;
        f32x2 qv = {q, q};
        h2[0] = P0 * h2[0] + qv * (f32x2){B0.x, B0.y};
        h2[1] = P1 * h2[1] + qv * (f32x2){B0.z, B0.w};
        h2[2] = P2 * h2[2] + qv * (f32x2){B1.x, B1.y};
        h2[3] = P3 * h2[3] + qv * (f32x2){B1.z, B1.w};
        h2[4] = P4 * h2[4] + qv * (f32x2){B2.x, B2.y};
        h2[5] = P5 * h2[5] + qv * (f32x2){B2.z, B2.w};
        h2[6] = P6 * h2[6] + qv * (f32x2){B3.x, B3.y};
        h2[7] = P7 * h2[7] + qv * (f32x2){B3.z, B3.w};
      }
      *(uint4*)(dtp + tg) = make_uint4(dqw[0], dqw[1], dqw[2], dqw[3]);
    }
    #pragma unroll
    for (int j = 0; j < 8; j += 2)
      *(float4*)(hend + o + j * 2) =
          make_float4(h2[j].x, h2[j].y, h2[j + 1].x, h2[j + 1].y);
  } else {
    float h[NST];
    #pragma unroll
    for (int j = 0; j < NST; j++) h[j] = 0.f;
    for (int t = 0; t < CLEN; t++) {
      float acc = db;
      #pragma unroll
      for (int rr = 0; rr < 12; rr++) acc = fmaf(dblB[t * DBS + rr], w12[rr], acc);
      float dtv = (acc > 15.f) ? acc : __logf(1.f + __expf(acc));
      dtp[t] = f2h(dtv);
      float uv  = bf2f(ubp[t]);
      float q = dtv * uv;
      S += dtv;
      #pragma unroll
      for (int j = 0; j < NST; j++)
        h[j] = __expf(dtv * av_[j]) * h[j] + q * dblB[t * DBS + RDT + j];
    }
    #pragma unroll
    for (int j = 0; j < NST; j++) hend[o + j] = h[j];
  }
  Sbuf[(size_t)bd * NC + chunk] = S;
}

// ---------------------------------------------------------------------------
// Scan combine: decay products reconstructed as exp(S * av_s) from Sbuf.
__global__ __launch_bounds__(256) void scan_combine(
    float* __restrict__ hend, const float* __restrict__ Sbuf,
    const float* __restrict__ A_log) {
  __shared__ float sP[16][16], sH[16][16];
  int bd = blockIdx.x;
  int d = bd % DI;
  int s = threadIdx.x & 15, g = threadIdx.x >> 4;
  float av = -expf(A_log[d * NST + s]);
  size_t baseS = (size_t)bd * NC + g * NCH;
  size_t base = ((size_t)bd * NC + g * NCH) * NST + s;
  float Pl = 1.f, Hl = 0.f;
  #pragma unroll
  for (int k = 0; k < NCH; k++) {
    float p = __expf(Sbuf[baseS + k] * av);
    Hl = fmaf(p, Hl, hend[base + (size_t)k * NST]);
    Pl *= p;
  }
  sP[g][s] = Pl; sH[g][s] = Hl;
  __syncthreads();
  if (threadIdx.x < 16) {
    int ss = threadIdx.x;
    float c = 0.f;
    #pragma unroll
    for (int gg = 0; gg < 16; gg++) {
      float tmp = sH[gg][ss];
      float pp  = sP[gg][ss];
      sH[gg][ss] = c;
      c = fmaf(pp, c, tmp);
    }
  }
  __syncthreads();
  float c = sH[g][s];
  #pragma unroll
  for (int k = 0; k < NCH; k++) {
    size_t o = base + (size_t)k * NST;
    float p = __expf(Sbuf[baseS + k] * av);
    float he = hend[o];
    hend[o] = c;
    c = fmaf(p, c, he);
  }
}

// ---------------------------------------------------------------------------
// Scan phase 3: dt16/u_s read bulk [bd][t]; B/C via uniform s_loads (R11 arm);
// z strided; packed fp32 update; ym_t[t][d] bf16.
__global__ __launch_bounds__(128) void scan_phase3(
    const ushort_t* __restrict__ u_s, const float* __restrict__ dblT,
    const float* __restrict__ A_log, const ushort_t* __restrict__ dt16,
    const float* __restrict__ hin, const float* __restrict__ Dp,
    const ushort_t* __restrict__ xzT, ushort_t* __restrict__ ym_t) {
  int chunk = blockIdx.x, b = blockIdx.z;
  int d = blockIdx.y * 128 + threadIdx.x;
  int t0 = chunk * CLEN;
  const float* dblB = dblT + ((size_t)b * LL + t0) * DBS;  // uniform base
  int bd = b * DI + d;
  float av0 = -expf(A_log[d * NST]);
  float av_[NST];
  bool ok = true;
  #pragma unroll
  for (int j = 0; j < NST; j++) {
    av_[j] = -expf(A_log[d * NST + j]);
    ok = ok && (fabsf(av_[j] - av0 * (float)(j + 1)) <= 1e-4f * fabsf(av_[j]));
  }
  const ushort_t* ubp = u_s + (size_t)bd * LL + t0;
  const ushort_t* dtp = dt16 + (size_t)bd * LL + t0;
  const ushort_t* zp = xzT + ((size_t)b * LL + t0) * XZS + DI + d;
  ushort_t* ymp = ym_t + ((size_t)b * LL + t0) * DI + d;

  const float* hi = hin + ((size_t)bd * NC + chunk) * NST;
  float Dv = Dp[d];

  if (__all(ok)) {
    f32x2 h2[8];
    #pragma unroll
    for (int j = 0; j < 8; j += 2) {
      float4 v = *(const float4*)(hi + j * 2);
      h2[j]     = (f32x2){v.x, v.y};
      h2[j + 1] = (f32x2){v.z, v.w};
    }
    #pragma unroll
    for (int tg = 0; tg < CLEN; tg += 8) {
      uint4 uq = *(const uint4*)(ubp + tg);
      uint4 dq = *(const uint4*)(dtp + tg);
      const unsigned* uw = (const unsigned*)&uq;
      const unsigned* dw = (const unsigned*)&dq;
      #pragma unroll
      for (int k = 0; k < 8; k++) {
        int t = tg + k;
        float4 B0 = *(const float4*)(dblB + t * DBS + RDT + 0);
        float4 B1 = *(const float4*)(dblB + t * DBS + RDT + 4);
        float4 B2 = *(const float4*)(dblB + t * DBS + RDT + 8);
        float4 B3 = *(const float4*)(dblB + t * DBS + RDT + 12);
        float4 C0 = *(const float4*)(dblB + t * DBS + RDT + 16);
        float4 C1 = *(const float4*)(dblB + t * DBS + RDT + 20);
        float4 C2 = *(const float4*)(dblB + t * DBS + RDT + 24);
        float4 C3 = *(const float4*)(dblB + t * DBS + RDT + 28);
        float dtv = h2f((ushort_t)(dw[k >> 1] >> ((k & 1) * 16)));
        float uv  = bf2f((ushort_t)(uw[k >> 1] >> ((k & 1) * 16)));
        float zv  = bf2f(zp[(size_t)t * XZS]);
        float q = dtv * uv;
        float p1 = __expf(dtv * av0);
        float p2 = p1 * p1, p4 = p2 * p2, p8 = p4 * p4;
        f32x2 p2v = {p2, p2}, p4v = {p4, p4}, p8v = {p8, p8};
        f32x2 P0 = {p1, p2};
        f32x2 P1 = P0 * p2v;
        f32x2 P2 = P0 * p4v;
        f32x2 P3 = P1 * p4v;
        f32x2 P4 = P0 * p8v;
        f32x2 P5 = P1 * p8v;
        f32x2 P6 = P2 * p8v;
        f32x2 P7 = P3 * p8v;
        f32x2 qv = {q, q};
        f32x2 ya, yb;
        h2[0] = P0 * h2[0] + qv * (f32x2){B0.x, B0.y};  ya = h2[0] * (f32x2){C0.x, C0.y};
        h2[1] = P1 * h2[1] + qv * (f32x2){B0.z, B0.w};  yb = h2[1] * (f32x2){C0.z, C0.w};
        h2[2] = P2 * h2[2] + qv * (f32x2){B1.x, B1.y};  ya = h2[2] * (f32x2){C1.x, C1.y} + ya;
        h2[3] = P3 * h2[3] + qv * (f32x2){B1.z, B1.w};  yb = h2[3] * (f32x2){C1.z, C1.w} + yb;
        h2[4] = P4 * h2[4] + qv * (f32x2){B2.x, B2.y};  ya = h2[4] * (f32x2){C2.x, C2.y} + ya;
        h2[5] = P5 * h2[5] + qv * (f32x2){B2.z, B2.w};  yb = h2[5] * (f32x2){C2.z, C2.w} + yb;
        h2[6] = P6 * h2[6] + qv * (f32x2){B3.x, B3.y};  ya = h2[6] * (f32x2){C3.x, C3.y} + ya;
        h2[7] = P7 * h2[7] + qv * (f32x2){B3.z, B3.w};  yb = h2[7] * (f32x2){C3.z, C3.w} + yb;
        float y = (ya.x + ya.y) + (yb.x + yb.y);
        float yv = (y + uv * Dv) * (zv / (1.f + __expf(-zv)));
        ymp[(size_t)t * DI] = f2bf(yv);
      }
    }
  } else {
    float h[NST];
    #pragma unroll
    for (int j = 0; j < NST; j++) h[j] = hi[j];
    for (int t = 0; t < CLEN; t++) {
      float dtv = h2f(dtp[t]);
      float uv  = bf2f(ubp[t]);
      float zv  = bf2f(zp[(size_t)t * XZS]);
      float q = dtv * uv;
      float y = 0.f;
      #pragma unroll
      for (int j = 0; j < NST; j++) {
        h[j] = __expf(dtv * av_[j]) * h[j] + q * dblB[t * DBS + RDT + j];
        y = fmaf(h[j], dblB[t * DBS + RDT + NST + j], y);
      }
      float yv = (y + uv * Dv) * (zv / (1.f + __expf(-zv)));
      ymp[(size_t)t * DI] = f2bf(yv);
    }
  }
}

// ---------------------------------------------------------------------------
extern "C" void kernel_launch(void* const* d_in, const int* in_sizes, int n_in,
                              void* d_out, int out_size, void* d_ws, size_t ws_size,
                              hipStream_t stream) {
  const float* x         = (const float*)d_in[0];
  const float* in_proj_w = (const float*)d_in[1];
  const float* conv_w    = (const float*)d_in[2];
  const float* conv_b    = (const float*)d_in[3];
  const float* x_proj_w  = (const float*)d_in[4];
  const float* dt_proj_w = (const float*)d_in[5];
  const float* dt_proj_b = (const float*)d_in[6];
  const float* A_log     = (const float*)d_in[7];
  const float* D_param   = (const float*)d_in[8];
  const float* out_proj_w= (const float*)d_in[9];
  const float* proj_w    = (const float*)d_in[10];
  const float* proj_b    = (const float*)d_in[11];
  float* out = (float*)d_out;

  // workspace layout (float units)
  float* w = (float*)d_ws;
  float*    mu     = w;                                   // 512
  float*    rstd   = w + 512;                             // 512
  float*    PW     = w + 1024;                            // 73,728
  ushort_t* PW_bf  = (ushort_t*)(w + 74752);              // 256x384 bf16 (49,152 f)
  ushort_t* ipw_bf = (ushort_t*)(w + 123904);             // 768x192 bf16 (73,728 f)
  ushort_t* xpw_bf = (ushort_t*)(w + 197632);             // 128x384 bf16 (24,576 f)
  ushort_t* xT     = (ushort_t*)(w + 222208);             // 6.29M bf16 (3,145,728 f)
  ushort_t* xzT    = (ushort_t*)(w + 3367936);            // 25.2M bf16 (12,582,912 f)
  ushort_t* u_t    = (ushort_t*)(w + 15950848);           // 12.6M bf16 (6,291,456 f)
  float*    dblT   = w + 22242304;                        // 2,097,152 f
  ushort_t* ym_t   = (ushort_t*)(w + 24339456);           // 12.6M bf16 (6,291,456 f)
  float*    hend   = w + 30630912;                        // 6,291,456 f (NC=512)
  float*    Sbuf   = w + 36922368;                        // 393,216 f
  ushort_t* dt16   = (ushort_t*)(w + 37315584);           // 12.6M fp16 (6,291,456 f) [bd][t]
  ushort_t* u_s    = (ushort_t*)(w + 43607040);           // 12.6M bf16 (6,291,456 f) [bd][t]
  size_t need = 49898496;
  if (ws_size < need * sizeof(float)) return;

  norm_stats_kernel<<<dim3(BB * CM), dim3(256), 0, stream>>>(x, mu, rstd);
  fuse_proj_kernel<<<dim3((CM * DI + 255) / 256), dim3(256), 0, stream>>>(proj_w, out_proj_w, PW);
  cvt_weights_kernel<<<dim3((2 * DI * CM + 255) / 256), dim3(256), 0, stream>>>(
      in_proj_w, x_proj_w, PW, ipw_bf, xpw_bf, PW_bf);
  xt_norm_kernel<<<dim3(LL / 64, CM / 64, BB), dim3(256), 0, stream>>>(x, mu, rstd, xT);

  // GEMM1: xzT[b][t][768] = xT(BT) x in_proj_w   (M=768 => MT=6, K=192)
  gemm_lds<true, ushort_t><<<dim3(256 * 6), dim3(256), 0, stream>>>(
      ipw_bf, xT, xzT, CM, 768, 6, (long)LL * CM, (long)LL * XZS, XZS, nullptr);

  conv_silu_kernel<<<dim3(LL / CVT, BB), dim3(384), 0, stream>>>(xzT, conv_w, conv_b, u_t, u_s);

  // GEMM2: dblT[b][t][64] = u_t(BT) x x_proj_w(padded 128)  (Mreal=64, MT=1, K=384)
  gemm_lds<true, float><<<dim3(256 * 1), dim3(256), 0, stream>>>(
      xpw_bf, u_t, dblT, DI, 64, 1, (long)LL * DI, (long)LL * DBS, DBS, nullptr);

  scan_phase1<<<dim3(NC, 3, BB), dim3(128), 0, stream>>>(
      u_s, dblT, A_log, dt_proj_w, dt_proj_b, hend, Sbuf, dt16);
  scan_combine<<<dim3(BB * DI), dim3(256), 0, stream>>>(hend, Sbuf, A_log);
  scan_phase3<<<dim3(NC, 3, BB), dim3(128), 0, stream>>>(
      u_s, dblT, A_log, dt16, hend, D_param, xzT, ym_t);

  // GEMM3: out[b][192][L] = PW(padded 256) x ym_t(BT) + proj_b  (Mreal=192, MT=2, K=384)
  gemm_lds<false, float><<<dim3(256 * 2), dim3(256), 0, stream>>>(
      PW_bf, ym_t, out, DI, CM, 2, (long)LL * DI, (long)CM * LL, LL, proj_b);
}

// Round 18
// 183.734 us; speedup vs baseline: 1.3046x; 1.2613x over previous
//
#include <hip/hip_runtime.h>
#include <hip/hip_bf16.h>
#include <hip/hip_fp16.h>
#include <math.h>

// Problem constants
#define BB   2
#define CM   192        // D_MODEL
#define DI   384        // D_INNER
#define LL   16384      // D*H*W
#define NST  16         // D_STATE
#define RDT  12         // DT_RANK
#define XJ   44         // DT_RANK + 2*D_STATE
#define NC   512        // scan chunks
#define CLEN 32         // chunk length (NC*CLEN == LL)
#define NCH  (NC / 16)  // chunks per combine-thread
#define DBS  64         // dblT row stride (GEMM2 padded M)
#define XZS  768        // xzT row stride
#define CVT  32         // conv t-tile
#define BK   32         // GEMM k-tile

typedef __attribute__((ext_vector_type(8))) short bf16x8;
typedef __attribute__((ext_vector_type(4))) float f32x4;
typedef __attribute__((ext_vector_type(2))) float f32x2;
typedef unsigned short ushort_t;

static __device__ __forceinline__ ushort_t f2bf(float f) {
  __hip_bfloat16 h = __float2bfloat16(f);
  return *reinterpret_cast<ushort_t*>(&h);
}
static __device__ __forceinline__ float bf2f(ushort_t u) {
  __hip_bfloat16 h;
  *reinterpret_cast<ushort_t*>(&h) = u;
  return __bfloat162float(h);
}
static __device__ __forceinline__ ushort_t f2h(float f) {
  __half h = __float2half(f);
  return *reinterpret_cast<ushort_t*>(&h);
}
static __device__ __forceinline__ float h2f(ushort_t u) {
  __half h;
  *reinterpret_cast<ushort_t*>(&h) = u;
  return __half2float(h);
}
static __device__ __forceinline__ unsigned pk2bf(float lo, float hi) {
  return (unsigned)f2bf(lo) | ((unsigned)f2bf(hi) << 16);
}

// ---------------------------------------------------------------------------
// PW = proj_w(192x192) @ out_proj_w(192x384)   (fp32, tiny)
__global__ __launch_bounds__(256) void fuse_proj_kernel(
    const float* __restrict__ pw, const float* __restrict__ ow, float* __restrict__ PW) {
  int idx = blockIdx.x * 256 + threadIdx.x;
  if (idx >= CM * DI) return;
  int o = idx / DI, d = idx % DI;
  float s = 0.f;
  #pragma unroll 4
  for (int c = 0; c < CM; c++) s += pw[o * CM + c] * ow[c * DI + d];
  PW[idx] = s;
}

// ---------------------------------------------------------------------------
// Weight conversions to bf16. Row-padding with zeros.
__global__ __launch_bounds__(256) void cvt_weights_kernel(
    const float* __restrict__ ipw, const float* __restrict__ xpw,
    const float* __restrict__ PW,
    ushort_t* __restrict__ ipw_bf, ushort_t* __restrict__ xpw_bf,
    ushort_t* __restrict__ PW_bf) {
  int i = blockIdx.x * 256 + threadIdx.x;
  if (i < 2 * DI * CM) ipw_bf[i] = f2bf(ipw[i]);
  if (i < 128 * DI) {
    int r = i / DI;
    xpw_bf[i] = (r < XJ) ? f2bf(xpw[i]) : (ushort_t)0;
  }
  if (i < 256 * DI) {
    int r = i / DI;
    PW_bf[i] = (r < CM) ? f2bf(PW[i]) : (ushort_t)0;
  }
}

// ---------------------------------------------------------------------------
// per-(b,c) mean / rstd over L
__global__ __launch_bounds__(256) void norm_stats_kernel(
    const float* __restrict__ x, float* __restrict__ mu, float* __restrict__ rstd) {
  int bc = blockIdx.x;
  const float* p = x + (size_t)bc * LL;
  float s = 0.f, ss = 0.f;
  for (int i = threadIdx.x * 4; i < LL; i += 256 * 4) {
    float4 v = *(const float4*)(p + i);
    s += v.x + v.y + v.z + v.w;
    ss += v.x * v.x + v.y * v.y + v.z * v.z + v.w * v.w;
  }
  for (int o = 32; o > 0; o >>= 1) {
    s += __shfl_down(s, o, 64);
    ss += __shfl_down(ss, o, 64);
  }
  __shared__ float sb[4], ssb[4];
  int wid = threadIdx.x >> 6;
  if ((threadIdx.x & 63) == 0) { sb[wid] = s; ssb[wid] = ss; }
  __syncthreads();
  if (threadIdx.x == 0) {
    s = sb[0] + sb[1] + sb[2] + sb[3];
    ss = ssb[0] + ssb[1] + ssb[2] + ssb[3];
    float m = s * (1.f / LL);
    float var = ss * (1.f / LL) - m * m;
    mu[bc] = m;
    rstd[bc] = 1.f / sqrtf(var + 1e-5f);
  }
}

// ---------------------------------------------------------------------------
// xT[b][t][c] bf16 = normalized x (LDS 64x64 transpose tile)
__global__ __launch_bounds__(256) void xt_norm_kernel(
    const float* __restrict__ x, const float* __restrict__ mu,
    const float* __restrict__ rstd, ushort_t* __restrict__ xT) {
  __shared__ ushort_t T[64][72];
  int t0 = blockIdx.x * 64, c0 = blockIdx.y * 64, b = blockIdx.z;
  int tid = threadIdx.x;
  int c = tid >> 2, tq = (tid & 3) * 16;
  int bc = b * CM + c0 + c;
  const float* xp = x + (size_t)bc * LL + t0 + tq;
  float m = mu[bc], rs = rstd[bc];
  #pragma unroll
  for (int j = 0; j < 16; j += 4) {
    float4 v = *(const float4*)(xp + j);
    T[c][tq + j + 0] = f2bf((v.x - m) * rs);
    T[c][tq + j + 1] = f2bf((v.y - m) * rs);
    T[c][tq + j + 2] = f2bf((v.z - m) * rs);
    T[c][tq + j + 3] = f2bf((v.w - m) * rs);
  }
  __syncthreads();
  int t = tid >> 2, cq = (tid & 3) * 16;
  unsigned int ob[8];
  #pragma unroll
  for (int j = 0; j < 8; j++)
    ob[j] = (unsigned int)T[cq + 2 * j][t] | ((unsigned int)T[cq + 2 * j + 1][t] << 16);
  ushort_t* op = xT + ((size_t)b * LL + t0 + t) * CM + c0 + cq;
  *(uint4*)(op)     = make_uint4(ob[0], ob[1], ob[2], ob[3]);
  *(uint4*)(op + 8) = make_uint4(ob[4], ob[5], ob[6], ob[7]);
}

// ---------------------------------------------------------------------------
// LDS-pipelined MFMA bf16 GEMM (BK=32 double-buffer, global_load_lds).
template <bool TOUT, typename OutT>
__global__ __launch_bounds__(256) void gemm_lds(
    const ushort_t* __restrict__ A, const ushort_t* __restrict__ BT,
    OutT* __restrict__ C, int K, int Mreal, int MT,
    long strideBT, long strideC, int ldc,
    const float* __restrict__ bias) {
  __shared__ ushort_t Asm[2][128 * BK];
  __shared__ ushort_t Bsm[2][128 * BK];

  int id = blockIdx.x;
  int per = MT * 8;
  int g = id / per, r = id % per;
  int nt = g * 8 + (r & 7);
  int mt = r >> 3;
  int b  = nt >> 7;
  long n0 = (long)(nt & 127) * 128;
  int m0 = mt * 128;

  int tid = threadIdx.x;
  int lane = tid & 63, wave = tid >> 6;
  const ushort_t* Bbase = BT + (size_t)b * strideBT;

  int srow0 = wave * 32 + (lane >> 2);
  int sk = (lane & 3) * 8;

  f32x4 acc[4][4];
  #pragma unroll
  for (int mi = 0; mi < 4; mi++)
    #pragma unroll
    for (int ni = 0; ni < 4; ni++) acc[mi][ni] = (f32x4){0.f, 0.f, 0.f, 0.f};

  int mh = wave & 1, nh = wave >> 1;
  int fr = lane & 15, fk = (lane >> 4) * 8;

  int nsteps = K / BK;
  {
    const ushort_t* As0 = A + (size_t)(m0 + srow0) * K + sk;
    const ushort_t* Bs0 = Bbase + (size_t)(n0 + srow0) * K + sk;
    __builtin_amdgcn_global_load_lds(As0, &Asm[0][wave * 1024], 16, 0, 0);
    __builtin_amdgcn_global_load_lds(As0 + (size_t)16 * K, &Asm[0][wave * 1024 + 512], 16, 0, 0);
    __builtin_amdgcn_global_load_lds(Bs0, &Bsm[0][wave * 1024], 16, 0, 0);
    __builtin_amdgcn_global_load_lds(Bs0 + (size_t)16 * K, &Bsm[0][wave * 1024 + 512], 16, 0, 0);
  }
  __syncthreads();
  int cur = 0;
  for (int s = 0; s < nsteps; s++) {
    if (s + 1 < nsteps) {
      int k0 = (s + 1) * BK;
      const ushort_t* As0 = A + (size_t)(m0 + srow0) * K + k0 + sk;
      const ushort_t* Bs0 = Bbase + (size_t)(n0 + srow0) * K + k0 + sk;
      __builtin_amdgcn_global_load_lds(As0, &Asm[cur ^ 1][wave * 1024], 16, 0, 0);
      __builtin_amdgcn_global_load_lds(As0 + (size_t)16 * K, &Asm[cur ^ 1][wave * 1024 + 512], 16, 0, 0);
      __builtin_amdgcn_global_load_lds(Bs0, &Bsm[cur ^ 1][wave * 1024], 16, 0, 0);
      __builtin_amdgcn_global_load_lds(Bs0 + (size_t)16 * K, &Bsm[cur ^ 1][wave * 1024 + 512], 16, 0, 0);
    }
    bf16x8 fa[4], fb[4];
    #pragma unroll
    for (int mi = 0; mi < 4; mi++)
      fa[mi] = *(const bf16x8*)&Asm[cur][(mh * 64 + mi * 16 + fr) * BK + fk];
    #pragma unroll
    for (int ni = 0; ni < 4; ni++)
      fb[ni] = *(const bf16x8*)&Bsm[cur][(nh * 64 + ni * 16 + fr) * BK + fk];
    #pragma unroll
    for (int mi = 0; mi < 4; mi++)
      #pragma unroll
      for (int ni = 0; ni < 4; ni++) {
        if constexpr (TOUT)
          acc[mi][ni] = __builtin_amdgcn_mfma_f32_16x16x32_bf16(fb[ni], fa[mi], acc[mi][ni], 0, 0, 0);
        else
          acc[mi][ni] = __builtin_amdgcn_mfma_f32_16x16x32_bf16(fa[mi], fb[ni], acc[mi][ni], 0, 0, 0);
      }
    __syncthreads();
    cur ^= 1;
  }

  int cq = (lane >> 4) * 4;
  if constexpr (TOUT) {
    #pragma unroll
    for (int ni = 0; ni < 4; ni++)
      #pragma unroll
      for (int rg = 0; rg < 4; rg++) {
        long n = n0 + nh * 64 + ni * 16 + cq + rg;
        OutT* cp = C + (size_t)b * strideC + n * ldc + m0 + mh * 64 + fr;
        #pragma unroll
        for (int mi = 0; mi < 4; mi++) {
          int mrow = m0 + mh * 64 + mi * 16 + fr;
          if (mrow < Mreal) {
            float v = acc[mi][ni][rg];
            if constexpr (sizeof(OutT) == 2) cp[mi * 16] = f2bf(v);
            else                             cp[mi * 16] = v;
          }
        }
      }
  } else {
    #pragma unroll
    for (int mi = 0; mi < 4; mi++)
      #pragma unroll
      for (int rg = 0; rg < 4; rg++) {
        int m = m0 + mh * 64 + mi * 16 + cq + rg;
        if (m < Mreal) {
          float bv = bias ? bias[m] : 0.f;
          OutT* cp = C + (size_t)b * strideC + (size_t)m * ldc + n0 + nh * 64 + fr;
          #pragma unroll
          for (int ni = 0; ni < 4; ni++)
            cp[ni * 16] = acc[mi][ni][rg] + bv;
        }
      }
  }
}

// ---------------------------------------------------------------------------
// Conv: causal depthwise k=4 + bias + SiLU.
__global__ __launch_bounds__(384) void conv_silu_kernel(
    const ushort_t* __restrict__ xzT, const float* __restrict__ conv_w,
    const float* __restrict__ conv_b, ushort_t* __restrict__ u_t) {
  __shared__ ushort_t Us[CVT + 3][DI];
  int t0 = blockIdx.x * CVT;
  int b = blockIdx.y;
  int tid = threadIdx.x;
  #pragma unroll
  for (int r = 0; r < CVT + 3; r++) {
    int t = t0 - 3 + r;
    Us[r][tid] = (t >= 0) ? xzT[((size_t)b * LL + t) * XZS + tid] : (ushort_t)0;
  }
  float w0 = conv_w[tid * 4 + 0], w1 = conv_w[tid * 4 + 1];
  float w2 = conv_w[tid * 4 + 2], w3 = conv_w[tid * 4 + 3];
  float cb = conv_b[tid];
  __syncthreads();
  ushort_t* up = u_t + ((size_t)b * LL + t0) * DI + tid;
  float xm3 = bf2f(Us[0][tid]);
  float xm2 = bf2f(Us[1][tid]);
  float xm1 = bf2f(Us[2][tid]);
  #pragma unroll
  for (int t = 0; t < CVT; t++) {
    float xc = bf2f(Us[t + 3][tid]);
    float a = cb + w3 * xc + w2 * xm1 + w1 * xm2 + w0 * xm3;
    float sv = a / (1.f + __expf(-a));
    up[(size_t)t * DI] = f2bf(sv);
    xm3 = xm2; xm2 = xm1; xm1 = xc;
  }
}

// ---------------------------------------------------------------------------
// Scan phase 1 (dt fused, packed fp32 state update). R11 structure;
// hend stored bf16 (math fp32). Block = 128 threads; grid (NC, 3, BB).
__global__ __launch_bounds__(128) void scan_phase1(
    const ushort_t* __restrict__ u_t, const float* __restrict__ dblT,
    const float* __restrict__ A_log,
    const float* __restrict__ dtw, const float* __restrict__ dtb,
    ushort_t* __restrict__ hend, float* __restrict__ Sbuf,
    ushort_t* __restrict__ dt16) {
  int chunk = blockIdx.x, b = blockIdx.z;
  int d = blockIdx.y * 128 + threadIdx.x;
  int t0 = chunk * CLEN;
  const float* dblB = dblT + ((size_t)b * LL + t0) * DBS;  // uniform base
  int bd = b * DI + d;
  float av0 = -expf(A_log[d * NST]);
  float av_[NST];
  bool ok = true;
  #pragma unroll
  for (int j = 0; j < NST; j++) {
    av_[j] = -expf(A_log[d * NST + j]);
    ok = ok && (fabsf(av_[j] - av0 * (float)(j + 1)) <= 1e-4f * fabsf(av_[j]));
  }
  float w12[12];
  #pragma unroll
  for (int rr = 0; rr < 12; rr += 4)
    *(float4*)(w12 + rr) = *(const float4*)(dtw + d * 12 + rr);
  float db = dtb[d];
  const ushort_t* up = u_t + ((size_t)b * LL + t0) * DI + d;
  ushort_t* dtp16 = dt16 + ((size_t)b * LL + t0) * DI + d;
  float S = 0.f;

  size_t o = ((size_t)bd * NC + chunk) * NST;
  if (__all(ok)) {
    f32x2 h2[8];
    #pragma unroll
    for (int j = 0; j < 8; j++) h2[j] = (f32x2){0.f, 0.f};
    #pragma unroll 4
    for (int t = 0; t < CLEN; t++) {
      float4 L0 = *(const float4*)(dblB + t * DBS + 0);
      float4 L1 = *(const float4*)(dblB + t * DBS + 4);
      float4 L2 = *(const float4*)(dblB + t * DBS + 8);
      float4 B0 = *(const float4*)(dblB + t * DBS + RDT + 0);
      float4 B1 = *(const float4*)(dblB + t * DBS + RDT + 4);
      float4 B2 = *(const float4*)(dblB + t * DBS + RDT + 8);
      float4 B3 = *(const float4*)(dblB + t * DBS + RDT + 12);
      float acc = db;
      acc = fmaf(L0.x, w12[0], acc); acc = fmaf(L0.y, w12[1], acc);
      acc = fmaf(L0.z, w12[2], acc); acc = fmaf(L0.w, w12[3], acc);
      acc = fmaf(L1.x, w12[4], acc); acc = fmaf(L1.y, w12[5], acc);
      acc = fmaf(L1.z, w12[6], acc); acc = fmaf(L1.w, w12[7], acc);
      acc = fmaf(L2.x, w12[8], acc); acc = fmaf(L2.y, w12[9], acc);
      acc = fmaf(L2.z, w12[10], acc); acc = fmaf(L2.w, w12[11], acc);
      float dtv = (acc > 15.f) ? acc : __logf(1.f + __expf(acc));
      dtp16[(size_t)t * DI] = f2h(dtv);
      float uv  = bf2f(up[(size_t)t * DI]);
      float q = dtv * uv;
      S += dtv;
      float p1 = __expf(dtv * av0);
      float p2 = p1 * p1, p4 = p2 * p2, p8 = p4 * p4;
      f32x2 p2v = {p2, p2}, p4v = {p4, p4}, p8v = {p8, p8};
      f32x2 P0 = {p1, p2};
      f32x2 P1 = P0 * p2v;
      f32x2 P2 = P0 * p4v;
      f32x2 P3 = P1 * p4v;
      f32x2 P4 = P0 * p8v;
      f32x2 P5 = P1 * p8v;
      f32x2 P6 = P2 * p8v;
      f32x2 P7 = P3 * p8v;
      f32x2 qv = {q, q};
      h2[0] = P0 * h2[0] + qv * (f32x2){B0.x, B0.y};
      h2[1] = P1 * h2[1] + qv * (f32x2){B0.z, B0.w};
      h2[2] = P2 * h2[2] + qv * (f32x2){B1.x, B1.y};
      h2[3] = P3 * h2[3] + qv * (f32x2){B1.z, B1.w};
      h2[4] = P4 * h2[4] + qv * (f32x2){B2.x, B2.y};
      h2[5] = P5 * h2[5] + qv * (f32x2){B2.z, B2.w};
      h2[6] = P6 * h2[6] + qv * (f32x2){B3.x, B3.y};
      h2[7] = P7 * h2[7] + qv * (f32x2){B3.z, B3.w};
    }
    unsigned pk[8];
    #pragma unroll
    for (int j = 0; j < 8; j++) pk[j] = pk2bf(h2[j].x, h2[j].y);
    *(uint4*)(hend + o)     = make_uint4(pk[0], pk[1], pk[2], pk[3]);
    *(uint4*)(hend + o + 8) = make_uint4(pk[4], pk[5], pk[6], pk[7]);
  } else {
    float h[NST];
    #pragma unroll
    for (int j = 0; j < NST; j++) h[j] = 0.f;
    for (int t = 0; t < CLEN; t++) {
      float acc = db;
      #pragma unroll
      for (int rr = 0; rr < 12; rr++) acc = fmaf(dblB[t * DBS + rr], w12[rr], acc);
      float dtv = (acc > 15.f) ? acc : __logf(1.f + __expf(acc));
      dtp16[(size_t)t * DI] = f2h(dtv);
      float uv  = bf2f(up[(size_t)t * DI]);
      float q = dtv * uv;
      S += dtv;
      #pragma unroll
      for (int j = 0; j < NST; j++)
        h[j] = __expf(dtv * av_[j]) * h[j] + q * dblB[t * DBS + RDT + j];
    }
    #pragma unroll
    for (int j = 0; j < NST; j++) hend[o + j] = f2bf(h[j]);
  }
  Sbuf[(size_t)bd * NC + chunk] = S;
}

// ---------------------------------------------------------------------------
// Scan combine: hend bf16 storage, fp32 math; decay via exp(S * av_s).
__global__ __launch_bounds__(256) void scan_combine(
    ushort_t* __restrict__ hend, const float* __restrict__ Sbuf,
    const float* __restrict__ A_log) {
  __shared__ float sP[16][16], sH[16][16];
  int bd = blockIdx.x;
  int d = bd % DI;
  int s = threadIdx.x & 15, g = threadIdx.x >> 4;
  float av = -expf(A_log[d * NST + s]);
  size_t baseS = (size_t)bd * NC + g * NCH;
  size_t base = ((size_t)bd * NC + g * NCH) * NST + s;
  float Pl = 1.f, Hl = 0.f;
  #pragma unroll
  for (int k = 0; k < NCH; k++) {
    float p = __expf(Sbuf[baseS + k] * av);
    Hl = fmaf(p, Hl, bf2f(hend[base + (size_t)k * NST]));
    Pl *= p;
  }
  sP[g][s] = Pl; sH[g][s] = Hl;
  __syncthreads();
  if (threadIdx.x < 16) {
    int ss = threadIdx.x;
    float c = 0.f;
    #pragma unroll
    for (int gg = 0; gg < 16; gg++) {
      float tmp = sH[gg][ss];
      float pp  = sP[gg][ss];
      sH[gg][ss] = c;
      c = fmaf(pp, c, tmp);
    }
  }
  __syncthreads();
  float c = sH[g][s];
  #pragma unroll
  for (int k = 0; k < NCH; k++) {
    size_t o = base + (size_t)k * NST;
    float p = __expf(Sbuf[baseS + k] * av);
    float he = bf2f(hend[o]);
    hend[o] = f2bf(c);
    c = fmaf(p, c, he);
  }
}

// ---------------------------------------------------------------------------
// Scan phase 3: R11 structure; hin read bf16; dt fp16; packed fp32 update.
__global__ __launch_bounds__(128) void scan_phase3(
    const ushort_t* __restrict__ u_t, const float* __restrict__ dblT,
    const float* __restrict__ A_log, const ushort_t* __restrict__ dt16,
    const ushort_t* __restrict__ hin, const float* __restrict__ Dp,
    const ushort_t* __restrict__ xzT, ushort_t* __restrict__ ym_t) {
  int chunk = blockIdx.x, b = blockIdx.z;
  int d = blockIdx.y * 128 + threadIdx.x;
  int t0 = chunk * CLEN;
  const float* dblB = dblT + ((size_t)b * LL + t0) * DBS;  // uniform base
  int bd = b * DI + d;
  float av0 = -expf(A_log[d * NST]);
  float av_[NST];
  bool ok = true;
  #pragma unroll
  for (int j = 0; j < NST; j++) {
    av_[j] = -expf(A_log[d * NST + j]);
    ok = ok && (fabsf(av_[j] - av0 * (float)(j + 1)) <= 1e-4f * fabsf(av_[j]));
  }
  const ushort_t* up = u_t + ((size_t)b * LL + t0) * DI + d;
  const ushort_t* zp = xzT + ((size_t)b * LL + t0) * XZS + DI + d;
  const ushort_t* dtp16 = dt16 + ((size_t)b * LL + t0) * DI + d;
  ushort_t* ymp = ym_t + ((size_t)b * LL + t0) * DI + d;

  const ushort_t* hi = hin + ((size_t)bd * NC + chunk) * NST;
  float Dv = Dp[d];

  if (__all(ok)) {
    f32x2 h2[8];
    {
      uint4 q0 = *(const uint4*)(hi);
      uint4 q1 = *(const uint4*)(hi + 8);
      const unsigned* qw0 = (const unsigned*)&q0;
      const unsigned* qw1 = (const unsigned*)&q1;
      #pragma unroll
      for (int j = 0; j < 4; j++) {
        h2[j]     = (f32x2){bf2f((ushort_t)(qw0[j] & 0xffff)), bf2f((ushort_t)(qw0[j] >> 16))};
        h2[j + 4] = (f32x2){bf2f((ushort_t)(qw1[j] & 0xffff)), bf2f((ushort_t)(qw1[j] >> 16))};
      }
    }
    #pragma unroll 4
    for (int t = 0; t < CLEN; t++) {
      float4 B0 = *(const float4*)(dblB + t * DBS + RDT + 0);
      float4 B1 = *(const float4*)(dblB + t * DBS + RDT + 4);
      float4 B2 = *(const float4*)(dblB + t * DBS + RDT + 8);
      float4 B3 = *(const float4*)(dblB + t * DBS + RDT + 12);
      float4 C0 = *(const float4*)(dblB + t * DBS + RDT + 16);
      float4 C1 = *(const float4*)(dblB + t * DBS + RDT + 20);
      float4 C2 = *(const float4*)(dblB + t * DBS + RDT + 24);
      float4 C3 = *(const float4*)(dblB + t * DBS + RDT + 28);
      float dtv = h2f(dtp16[(size_t)t * DI]);
      float uv  = bf2f(up[(size_t)t * DI]);
      float zv  = bf2f(zp[(size_t)t * XZS]);
      float q = dtv * uv;
      float p1 = __expf(dtv * av0);
      float p2 = p1 * p1, p4 = p2 * p2, p8 = p4 * p4;
      f32x2 p2v = {p2, p2}, p4v = {p4, p4}, p8v = {p8, p8};
      f32x2 P0 = {p1, p2};
      f32x2 P1 = P0 * p2v;
      f32x2 P2 = P0 * p4v;
      f32x2 P3 = P1 * p4v;
      f32x2 P4 = P0 * p8v;
      f32x2 P5 = P1 * p8v;
      f32x2 P6 = P2 * p8v;
      f32x2 P7 = P3 * p8v;
      f32x2 qv = {q, q};
      f32x2 ya, yb;
      h2[0] = P0 * h2[0] + qv * (f32x2){B0.x, B0.y};  ya = h2[0] * (f32x2){C0.x, C0.y};
      h2[1] = P1 * h2[1] + qv * (f32x2){B0.z, B0.w};  yb = h2[1] * (f32x2){C0.z, C0.w};
      h2[2] = P2 * h2[2] + qv * (f32x2){B1.x, B1.y};  ya = h2[2] * (f32x2){C1.x, C1.y} + ya;
      h2[3] = P3 * h2[3] + qv * (f32x2){B1.z, B1.w};  yb = h2[3] * (f32x2){C1.z, C1.w} + yb;
      h2[4] = P4 * h2[4] + qv * (f32x2){B2.x, B2.y};  ya = h2[4] * (f32x2){C2.x, C2.y} + ya;
      h2[5] = P5 * h2[5] + qv * (f32x2){B2.z, B2.w};  yb = h2[5] * (f32x2){C2.z, C2.w} + yb;
      h2[6] = P6 * h2[6] + qv * (f32x2){B3.x, B3.y};  ya = h2[6] * (f32x2){C3.x, C3.y} + ya;
      h2[7] = P7 * h2[7] + qv * (f32x2){B3.z, B3.w};  yb = h2[7] * (f32x2){C3.z, C3.w} + yb;
      float y = (ya.x + ya.y) + (yb.x + yb.y);
      float yv = (y + uv * Dv) * (zv / (1.f + __expf(-zv)));
      ymp[(size_t)t * DI] = f2bf(yv);
    }
  } else {
    float h[NST];
    #pragma unroll
    for (int j = 0; j < NST; j++) h[j] = bf2f(hi[j]);
    for (int t = 0; t < CLEN; t++) {
      float dtv = h2f(dtp16[(size_t)t * DI]);
      float uv  = bf2f(up[(size_t)t * DI]);
      float zv  = bf2f(zp[(size_t)t * XZS]);
      float q = dtv * uv;
      float y = 0.f;
      #pragma unroll
      for (int j = 0; j < NST; j++) {
        h[j] = __expf(dtv * av_[j]) * h[j] + q * dblB[t * DBS + RDT + j];
        y = fmaf(h[j], dblB[t * DBS + RDT + NST + j], y);
      }
      float yv = (y + uv * Dv) * (zv / (1.f + __expf(-zv)));
      ymp[(size_t)t * DI] = f2bf(yv);
    }
  }
}

// ---------------------------------------------------------------------------
extern "C" void kernel_launch(void* const* d_in, const int* in_sizes, int n_in,
                              void* d_out, int out_size, void* d_ws, size_t ws_size,
                              hipStream_t stream) {
  const float* x         = (const float*)d_in[0];
  const float* in_proj_w = (const float*)d_in[1];
  const float* conv_w    = (const float*)d_in[2];
  const float* conv_b    = (const float*)d_in[3];
  const float* x_proj_w  = (const float*)d_in[4];
  const float* dt_proj_w = (const float*)d_in[5];
  const float* dt_proj_b = (const float*)d_in[6];
  const float* A_log     = (const float*)d_in[7];
  const float* D_param   = (const float*)d_in[8];
  const float* out_proj_w= (const float*)d_in[9];
  const float* proj_w    = (const float*)d_in[10];
  const float* proj_b    = (const float*)d_in[11];
  float* out = (float*)d_out;

  // workspace layout (float units)
  float* w = (float*)d_ws;
  float*    mu     = w;                                   // 512
  float*    rstd   = w + 512;                             // 512
  float*    PW     = w + 1024;                            // 73,728
  ushort_t* PW_bf  = (ushort_t*)(w + 74752);              // 256x384 bf16 (49,152 f)
  ushort_t* ipw_bf = (ushort_t*)(w + 123904);             // 768x192 bf16 (73,728 f)
  ushort_t* xpw_bf = (ushort_t*)(w + 197632);             // 128x384 bf16 (24,576 f)
  ushort_t* xT     = (ushort_t*)(w + 222208);             // 6.29M bf16 (3,145,728 f)
  ushort_t* xzT    = (ushort_t*)(w + 3367936);            // 25.2M bf16 (12,582,912 f)
  ushort_t* u_t    = (ushort_t*)(w + 15950848);           // 12.6M bf16 (6,291,456 f)
  float*    dblT   = w + 22242304;                        // 2,097,152 f
  ushort_t* ym_t   = (ushort_t*)(w + 24339456);           // 12.6M bf16 (6,291,456 f)
  ushort_t* hend   = (ushort_t*)(w + 30630912);           // 12.6M bf16 (3,145,728 f)
  float*    Sbuf   = w + 33776640;                        // 393,216 f
  ushort_t* dt16   = (ushort_t*)(w + 34169856);           // 12.6M fp16 (6,291,456 f)
  size_t need = 40461312;
  if (ws_size < need * sizeof(float)) return;

  norm_stats_kernel<<<dim3(BB * CM), dim3(256), 0, stream>>>(x, mu, rstd);
  fuse_proj_kernel<<<dim3((CM * DI + 255) / 256), dim3(256), 0, stream>>>(proj_w, out_proj_w, PW);
  cvt_weights_kernel<<<dim3((2 * DI * CM + 255) / 256), dim3(256), 0, stream>>>(
      in_proj_w, x_proj_w, PW, ipw_bf, xpw_bf, PW_bf);
  xt_norm_kernel<<<dim3(LL / 64, CM / 64, BB), dim3(256), 0, stream>>>(x, mu, rstd, xT);

  // GEMM1: xzT[b][t][768] = xT(BT) x in_proj_w   (M=768 => MT=6, K=192)
  gemm_lds<true, ushort_t><<<dim3(256 * 6), dim3(256), 0, stream>>>(
      ipw_bf, xT, xzT, CM, 768, 6, (long)LL * CM, (long)LL * XZS, XZS, nullptr);

  conv_silu_kernel<<<dim3(LL / CVT, BB), dim3(384), 0, stream>>>(xzT, conv_w, conv_b, u_t);

  // GEMM2: dblT[b][t][64] = u_t(BT) x x_proj_w(padded 128)  (Mreal=64, MT=1, K=384)
  gemm_lds<true, float><<<dim3(256 * 1), dim3(256), 0, stream>>>(
      xpw_bf, u_t, dblT, DI, 64, 1, (long)LL * DI, (long)LL * DBS, DBS, nullptr);

  scan_phase1<<<dim3(NC, 3, BB), dim3(128), 0, stream>>>(
      u_t, dblT, A_log, dt_proj_w, dt_proj_b, hend, Sbuf, dt16);
  scan_combine<<<dim3(BB * DI), dim3(256), 0, stream>>>(hend, Sbuf, A_log);
  scan_phase3<<<dim3(NC, 3, BB), dim3(128), 0, stream>>>(
      u_t, dblT, A_log, dt16, hend, D_param, xzT, ym_t);

  // GEMM3: out[b][192][L] = PW(padded 256) x ym_t(BT) + proj_b  (Mreal=192, MT=2, K=384)
  gemm_lds<false, float><<<dim3(256 * 2), dim3(256), 0, stream>>>(
      PW_bf, ym_t, out, DI, CM, 2, (long)LL * DI, (long)CM * LL, LL, proj_b);
}